// Round 3
// baseline (472.705 us; speedup 1.0000x reference)
//
#include <hip/hip_runtime.h>
#include <stdint.h>

// ContextPeftAdaptorLora on MI355X.
// out = [x | mask*H] @ [W | 2*Bw]^T + b, K' = 2048+64 = 2112.
// R3: H-pass reverted to the R1-verified dataflow (LDS-staged fragments,
// verified D-mapping epilogue). Occupancy fixed by 16-row blocks with waves
// splitting the jt/H-column dimension (grid 1024 vs 256). pass0 + gemm_aug
// verbatim from R2/R1.

typedef __attribute__((ext_vector_type(8))) short bf16x8;   // 8 bf16 = 4 VGPR
typedef __attribute__((ext_vector_type(4))) float f32x4;    // MFMA C/D
typedef __attribute__((ext_vector_type(4))) unsigned short u16x4;
typedef __attribute__((ext_vector_type(8))) unsigned short u16x8;

#define GAS __attribute__((address_space(1)))
#define LAS __attribute__((address_space(3)))

static constexpr int BB   = 4;
static constexpr int SS   = 4096;
static constexpr int DIN  = 2048;
static constexpr int DOUT = 2048;
static constexpr int NADP = 4;
static constexpr int RR   = 16;
static constexpr int M    = BB * SS;          // 16384 rows
static constexpr int KA   = DIN + NADP * RR;  // 2112 augmented K
static constexpr float SCALE = 2.0f;          // lora_alpha / r

__device__ __forceinline__ unsigned short f2bf(float f) {
  union { float f; uint32_t u; } v; v.f = f;
  uint32_t u = v.u;
  return (unsigned short)((u + 0x7FFFu + ((u >> 16) & 1u)) >> 16);  // RNE
}

__device__ __forceinline__ u16x8 cvt8(float4 a, float4 b) {
  return u16x8{ f2bf(a.x), f2bf(a.y), f2bf(a.z), f2bf(a.w),
                f2bf(b.x), f2bf(b.y), f2bf(b.z), f2bf(b.w) };
}

// ---------------------------------------------------------------------------
// Pass 0: pure streaming fp32->bf16 conversion. x -> Xaug[:,0:2048),
// W -> Waug[:,0:2048), SCALE*Bw -> Waug[:,2048:2112). Grid-stride, no LDS.
// (verbatim R2; W/Bw parts bit-equivalent to R1's verified pass2)
// ---------------------------------------------------------------------------
__global__ __launch_bounds__(256) void pass0_convert(
    const float* __restrict__ x, const float* __restrict__ W,
    const float* __restrict__ Bw, unsigned short* __restrict__ Xaug,
    unsigned short* __restrict__ Waug)
{
  const int nth = gridDim.x * 256;
  const int t0 = blockIdx.x * 256 + threadIdx.x;

  const int XCH = M * (DIN / 8);       // 4,194,304 8-elem chunks
  for (int c = t0; c < XCH; c += nth) {
    int row = c >> 8, k = (c & 255) * 8;
    float4 a = *(const float4*)(x + (size_t)row * DIN + k);
    float4 b = *(const float4*)(x + (size_t)row * DIN + k + 4);
    *(u16x8*)(Xaug + (size_t)row * KA + k) = cvt8(a, b);
  }
  const int WCH = DOUT * (DIN / 8);    // 524,288 chunks
  for (int c = t0; c < WCH; c += nth) {
    int row = c >> 8, k = (c & 255) * 8;
    float4 a = *(const float4*)(W + (size_t)row * DIN + k);
    float4 b = *(const float4*)(W + (size_t)row * DIN + k + 4);
    *(u16x8*)(Waug + (size_t)row * KA + k) = cvt8(a, b);
  }
  const int BCH = DOUT * NADP * 2;     // 16,384 chunks of the Bw block
  for (int c = t0; c < BCH; c += nth) {
    int cn = c >> 1, half = c & 1;
    int col = cn >> 2, n = cn & 3;
    const float* src = Bw + ((size_t)n * DOUT + col) * RR + half * 8;
    float4 a = *(const float4*)src;
    float4 b = *(const float4*)(src + 4);
    float4 sa = { SCALE * a.x, SCALE * a.y, SCALE * a.z, SCALE * a.w };
    float4 sb = { SCALE * b.x, SCALE * b.y, SCALE * b.z, SCALE * b.w };
    *(u16x8*)(Waug + (size_t)col * KA + DIN + n * 16 + half * 8) = cvt8(sa, sb);
  }
}

// ---------------------------------------------------------------------------
// Pass 1: H = x @ A^T, masked, -> Xaug[:,2048:2112).
// R1-verified dataflow: fp32 x and A staged through LDS as bf16, fragment
// reads + MFMA + epilogue D-mapping identical to R1's pass1_xcvt_h. Only
// change: 16 rows/block (grid 1024, 4 blk/CU) with the 4 waves each owning
// one jt tile (16 H-columns) instead of 4 waves x 16 rows.
// ---------------------------------------------------------------------------
__global__ __launch_bounds__(256) void pass1_h(
    const float* __restrict__ x, const float* __restrict__ A,
    const float* __restrict__ mask, unsigned short* __restrict__ Xaug)
{
  __shared__ unsigned short xb[16 * 64];  // [row][k] bf16, 2 KB
  __shared__ unsigned short ab[64 * 64];  // [j][k]   bf16, 8 KB

  const int tid = threadIdx.x;
  const int rowBase = blockIdx.x * 16;
  const int w = tid >> 6, lane = tid & 63;
  const int quad = lane >> 4, m16 = lane & 15;

  f32x4 acc = f32x4{0.f, 0.f, 0.f, 0.f};

  for (int kc = 0; kc < DIN; kc += 64) {
    __syncthreads();  // protect LDS against overwrite while prior MFMA reads run
    {
      // x: 16 rows x 16 float4-chunks = 256 chunks, one per thread
      int r = tid >> 4, kch = tid & 15;
      float4 xv = *(const float4*)(x + (size_t)(rowBase + r) * DIN + kc + kch * 4);
      *(u16x4*)(xb + r * 64 + kch * 4) =
          u16x4{ f2bf(xv.x), f2bf(xv.y), f2bf(xv.z), f2bf(xv.w) };
    }
    #pragma unroll
    for (int l = 0; l < 4; ++l) {
      // A: 64 rows x 16 chunks = 1024 chunks (verbatim R1 A-staging)
      int v = l * 256 + tid;
      int r = v >> 4;               // A row (0..63)
      int k = (v & 15) * 4;
      float4 av = *(const float4*)(A + (size_t)r * DIN + kc + k);
      *(u16x4*)(ab + r * 64 + k) =
          u16x4{ f2bf(av.x), f2bf(av.y), f2bf(av.z), f2bf(av.w) };
    }
    __syncthreads();
    // wave w computes all 16 rows x H-columns [w*16, w*16+16)
    #pragma unroll
    for (int s = 0; s < 2; ++s) {
      bf16x8 xf = *(const bf16x8*)(xb + m16 * 64 + s * 32 + quad * 8);
      bf16x8 af = *(const bf16x8*)(ab + (w * 16 + m16) * 64 + s * 32 + quad * 8);
      acc = __builtin_amdgcn_mfma_f32_16x16x32_bf16(xf, af, acc, 0, 0, 0);
    }
  }

  // Epilogue (R1-verified D-mapping): col = lane&15, row = quad*4 + reg.
  // This wave's H columns are [w*16, w*16+16) -> adaptor n = w.
  #pragma unroll
  for (int r = 0; r < 4; ++r) {
    int grow = rowBase + quad * 4 + r;
    float h = acc[r] * mask[(size_t)w * M + grow];
    Xaug[(size_t)grow * KA + DIN + w * 16 + m16] = f2bf(h);
  }
}

// ---------------------------------------------------------------------------
// Pass 2: bf16 GEMM, out[M, DOUT] = Xaug @ Waug^T + b. (verbatim R1-verified;
// 128x128 tile, BK=64, global_load_lds(16B), XOR swizzle.)
// ---------------------------------------------------------------------------
__global__ __launch_bounds__(256, 3) void gemm_aug(
    const unsigned short* __restrict__ Xa, const unsigned short* __restrict__ Wa,
    const float* __restrict__ bias, float* __restrict__ out)
{
  __shared__ unsigned short lds_a[128 * 64];  // 16 KB
  __shared__ unsigned short lds_b[128 * 64];  // 16 KB

  const int tid = threadIdx.x;
  const int bn = blockIdx.x, bm = blockIdx.y;
  const int w = tid >> 6, lane = tid & 63;
  const int wm = w >> 1, wn = w & 1;          // 2x2 wave grid, 64x64 each
  const int quad = lane >> 4, m16 = lane & 15;

  f32x4 acc[4][4];
  #pragma unroll
  for (int i = 0; i < 4; ++i)
    #pragma unroll
    for (int j = 0; j < 4; ++j) acc[i][j] = f32x4{0.f, 0.f, 0.f, 0.f};

  const unsigned short* ga = Xa + (size_t)bm * 128 * KA;
  const unsigned short* gb = Wa + (size_t)bn * 128 * KA;

  size_t goff[4];
  int ldso[4];
  #pragma unroll
  for (int l = 0; l < 4; ++l) {
    int p = l * 256 + tid;
    int r = p >> 3;                 // tile row 0..127
    int c = (p & 7) ^ (r & 7);      // swizzled global chunk
    goff[l] = (size_t)r * KA + c * 8;
    ldso[l] = (l * 256 + (tid & ~63)) * 8;     // wave-uniform LDS base
  }

  for (int k0 = 0; k0 < KA; k0 += 64) {
    __syncthreads();
    #pragma unroll
    for (int l = 0; l < 4; ++l) {
      __builtin_amdgcn_global_load_lds((const GAS void*)(ga + goff[l] + k0),
                                       (LAS void*)(lds_a + ldso[l]), 16, 0, 0);
      __builtin_amdgcn_global_load_lds((const GAS void*)(gb + goff[l] + k0),
                                       (LAS void*)(lds_b + ldso[l]), 16, 0, 0);
    }
    __syncthreads();

    #pragma unroll
    for (int s = 0; s < 2; ++s) {
      const int cc = ((s * 4 + quad) ^ (m16 & 7)) * 8;
      bf16x8 af[4], bfg[4];
      #pragma unroll
      for (int i = 0; i < 4; ++i)
        af[i] = *(const bf16x8*)(lds_a + (wm * 64 + i * 16 + m16) * 64 + cc);
      #pragma unroll
      for (int j = 0; j < 4; ++j)
        bfg[j] = *(const bf16x8*)(lds_b + (wn * 64 + j * 16 + m16) * 64 + cc);
      #pragma unroll
      for (int i = 0; i < 4; ++i)
        #pragma unroll
        for (int j = 0; j < 4; ++j)
          acc[i][j] = __builtin_amdgcn_mfma_f32_16x16x32_bf16(af[i], bfg[j],
                                                              acc[i][j], 0, 0, 0);
    }
  }

  float bv[4];
  #pragma unroll
  for (int j = 0; j < 4; ++j) bv[j] = bias[bn * 128 + wn * 64 + j * 16 + m16];
  #pragma unroll
  for (int i = 0; i < 4; ++i) {
    const int row0 = bm * 128 + wm * 64 + i * 16 + quad * 4;
    #pragma unroll
    for (int j = 0; j < 4; ++j) {
      const int col = bn * 128 + wn * 64 + j * 16 + m16;
      #pragma unroll
      for (int r = 0; r < 4; ++r)
        out[(size_t)(row0 + r) * DOUT + col] = acc[i][j][r] + bv[j];
    }
  }
}

// ---------------------------------------------------------------------------
extern "C" void kernel_launch(void* const* d_in, const int* in_sizes, int n_in,
                              void* d_out, int out_size, void* d_ws, size_t ws_size,
                              hipStream_t stream) {
  const float* x    = (const float*)d_in[0];  // [4,4096,2048]
  const float* mask = (const float*)d_in[1];  // [4,4,4096,1]
  const float* W    = (const float*)d_in[2];  // [2048,2048]
  const float* bias = (const float*)d_in[3];  // [2048]
  const float* A    = (const float*)d_in[4];  // [4,16,2048] -> flat [64,2048]
  const float* Bw   = (const float*)d_in[5];  // [4,2048,16]
  float* out = (float*)d_out;

  // workspace: Xaug [16384,2112] bf16 (69.2 MB) + Waug [2048,2112] bf16 (8.7 MB)
  unsigned short* Xaug = (unsigned short*)d_ws;
  unsigned short* Waug = Xaug + (size_t)M * KA;

  pass0_convert<<<dim3(2048), dim3(256), 0, stream>>>(x, W, Bw, Xaug, Waug);
  pass1_h<<<dim3(M / 16), dim3(256), 0, stream>>>(x, A, mask, Xaug);
  gemm_aug<<<dim3(DOUT / 128, M / 128), dim3(256), 0, stream>>>(Xaug, Waug, bias, out);
}